// Round 12
// baseline (329.740 us; speedup 1.0000x reference)
//
#include <hip/hip_runtime.h>
#include <math.h>

#define FD  128   // feature dim
#define CAP 64    // adjacency bucket capacity; deg~Poisson(12): P(deg>64)*N ~ 1e-16 -> no drops

static __device__ __forceinline__ float4 ld4(const float* p){ return *(const float4*)p; }

// ---------------- edge bucketing (replaces CSR scan pipeline) ----------------
// cnt[d] ends as true in-degree (excl self-loop); bcol[d*CAP + 0..deg) = sources.
// cnt is zeroed by k_gemm #1's prologue (runs before this in stream order).

__global__ __launch_bounds__(256) void k_fill(const int* __restrict__ src, const int* __restrict__ dst,
                                              int* __restrict__ cnt, int* __restrict__ bcol, int e){
    int i = blockIdx.x*blockDim.x + threadIdx.x;
    if (i < e){
        int s = src[i], d = dst[i];
        int pos = atomicAdd(&cnt[d], 1);
        if (pos < CAP) bcol[d*CAP + pos] = s;
    }
}

// ---------------- fp32 GEMM: out[i][j] = sum_k A[i][k] * W[j][k] ----------------
// 32-row x 128-col block tile, 256 threads, thread tile 2 rows x (4+4) cols.
// Additive float4-group swizzle on both LDS buffers:
//   Wt phys(k,j) = k*128 + 4*(((j>>2) + 2k) & 31) + (j&3)
//   xs phys(r,k) = r*128 + 4*(((k>>2) + r)  & 31) + (k&3)
// Verified: store group jg+2k == read group tc+2k (mod 32) -> cols 4tc..4tc+3.
// Banks: staging stores 2-way (free, m136); W b128 reads 16 consecutive quads,
// 4-way same-address broadcast (free); xs reads collapse to 2-4 unique addrs.
// LDS 64KB+16KB = 80KB static (gfx950 accepts up to 160KB/WG static LDS —
// precedent: learn_hip m201 128KiB plain-HIP kernel) -> 2 blocks/CU; staging
// of one block overlaps compute of the other. Also zero-fills cnt[0..zn)
// in its prologue (grid 8*nrows threads >= zn = nrows).

__global__ __launch_bounds__(256, 2) void k_gemm(const float* __restrict__ A, const float* __restrict__ W,
                                                 float* __restrict__ out, int nrows,
                                                 int* __restrict__ zcnt, int zn)
{
    __shared__ float Wt[128*128];
    __shared__ float xs[32*128];
    const int tid  = threadIdx.x;
    const int row0 = blockIdx.x * 32;

    int gid = blockIdx.x*256 + tid;
    if (zcnt && gid < zn) zcnt[gid] = 0;

    #pragma unroll
    for (int it = 0; it < 16; ++it){
        int idx4 = it*256 + tid;              // [0,4096)
        int j  = idx4 & 127;
        int k0 = (idx4 >> 7) << 2;
        float4 w = ld4(W + j*FD + k0);
        int jg = j >> 2, je = j & 3;
        Wt[(k0+0)*128 + (((jg + 2*(k0+0)) & 31) << 2) + je] = w.x;
        Wt[(k0+1)*128 + (((jg + 2*(k0+1)) & 31) << 2) + je] = w.y;
        Wt[(k0+2)*128 + (((jg + 2*(k0+2)) & 31) << 2) + je] = w.z;
        Wt[(k0+3)*128 + (((jg + 2*(k0+3)) & 31) << 2) + je] = w.w;
    }
    #pragma unroll
    for (int it = 0; it < 4; ++it){
        int idx4 = it*256 + tid;              // [0,1024)
        int r  = idx4 >> 5;
        int kq = idx4 & 31;
        int row = row0 + r;
        float4 v = make_float4(0.f,0.f,0.f,0.f);
        if (row < nrows) v = ld4(A + (size_t)row*FD + kq*4);
        *(float4*)&xs[r*128 + (((kq + r) & 31) << 2)] = v;
    }
    __syncthreads();

    const int tr = tid >> 4;    // rows 2tr, 2tr+1
    const int tc = tid & 15;    // cols 4tc..+3 and 64+4tc..+3
    float acc[2][2][4];
    #pragma unroll
    for (int i = 0; i < 2; ++i)
        #pragma unroll
        for (int hh = 0; hh < 2; ++hh)
            #pragma unroll
            for (int u = 0; u < 4; ++u) acc[i][hh][u] = 0.f;

    #pragma unroll 4
    for (int k0 = 0; k0 < 128; k0 += 4){
        int kq = k0 >> 2;
        float4 a0 = *(const float4*)&xs[(2*tr+0)*128 + (((kq + 2*tr+0) & 31) << 2)];
        float4 a1 = *(const float4*)&xs[(2*tr+1)*128 + (((kq + 2*tr+1) & 31) << 2)];
        #pragma unroll
        for (int kk = 0; kk < 4; ++kk){
            int k = k0 + kk;
            float4 w0 = *(const float4*)&Wt[k*128 + (((tc      + 2*k) & 31) << 2)];
            float4 w1 = *(const float4*)&Wt[k*128 + (((tc + 16 + 2*k) & 31) << 2)];
            float av0 = (kk==0)?a0.x:(kk==1)?a0.y:(kk==2)?a0.z:a0.w;
            float av1 = (kk==0)?a1.x:(kk==1)?a1.y:(kk==2)?a1.z:a1.w;
            acc[0][0][0] += av0*w0.x; acc[0][0][1] += av0*w0.y; acc[0][0][2] += av0*w0.z; acc[0][0][3] += av0*w0.w;
            acc[0][1][0] += av0*w1.x; acc[0][1][1] += av0*w1.y; acc[0][1][2] += av0*w1.z; acc[0][1][3] += av0*w1.w;
            acc[1][0][0] += av1*w0.x; acc[1][0][1] += av1*w0.y; acc[1][0][2] += av1*w0.z; acc[1][0][3] += av1*w0.w;
            acc[1][1][0] += av1*w1.x; acc[1][1][1] += av1*w1.y; acc[1][1][2] += av1*w1.z; acc[1][1][3] += av1*w1.w;
        }
    }

    #pragma unroll
    for (int i = 0; i < 2; ++i){
        int row = row0 + 2*tr + i;
        if (row < nrows){
            *(float4*)(out + (size_t)row*FD + 4*tc)      = make_float4(acc[i][0][0],acc[i][0][1],acc[i][0][2],acc[i][0][3]);
            *(float4*)(out + (size_t)row*FD + 64 + 4*tc) = make_float4(acc[i][1][0],acc[i][1][1],acc[i][1][2],acc[i][1][3]);
        }
    }
}

// ---------------- aggregation ----------------
// out[i] = relu(b + dinv_i^2 * t[i] + sum_e dinv_i*dinv_src * t[src_e])
// One wave per dst node, float2/lane. Adjacency preloaded one-edge-per-lane
// (coalesced 256B), per-src dinv gathered+rsqrt'd in parallel, broadcast via
// __shfl; gather loop unrolled x4 so 4 rows are in flight. Intra-graph
// self-edges flow through the bucket path with weight dinv^2, matching ref.

__global__ __launch_bounds__(256) void k_agg(const float* __restrict__ t, const float* __restrict__ bias,
    const int* __restrict__ cnt, const int* __restrict__ bcol,
    float* __restrict__ out, int n, int relu)
{
    int node = (blockIdx.x*blockDim.x + threadIdx.x) >> 6;
    int lane = threadIdx.x & 63;
    if (node >= n) return;

    // issue all independent loads up front (in flight during the gather loop)
    float2 b   = *(const float2*)(bias + lane*2);
    int deg = cnt[node];                       // true in-degree (excl self-loop)
    int dg  = min(deg, CAP);
    float dv = rsqrtf((float)(deg + 1));       // +1: self-loop appended by reference

    int   c_l = 0; float w_l = 0.f;
    if (lane < dg){
        c_l = bcol[node*CAP + lane];
        w_l = dv * rsqrtf((float)(cnt[c_l] + 1));
    }

    float2 acc = *(const float2*)(t + (size_t)node*FD + lane*2);
    float sw = dv*dv;
    acc.x = acc.x*sw + b.x;
    acc.y = acc.y*sw + b.y;

    int e = 0;
    for (; e + 4 <= dg; e += 4){
        int   c0 = __shfl(c_l, e,   64), c1 = __shfl(c_l, e+1, 64);
        int   c2 = __shfl(c_l, e+2, 64), c3 = __shfl(c_l, e+3, 64);
        float w0 = __shfl(w_l, e,   64), w1 = __shfl(w_l, e+1, 64);
        float w2 = __shfl(w_l, e+2, 64), w3 = __shfl(w_l, e+3, 64);
        float2 u0 = *(const float2*)(t + (size_t)c0*FD + lane*2);
        float2 u1 = *(const float2*)(t + (size_t)c1*FD + lane*2);
        float2 u2 = *(const float2*)(t + (size_t)c2*FD + lane*2);
        float2 u3 = *(const float2*)(t + (size_t)c3*FD + lane*2);
        acc.x += w0*u0.x + w1*u1.x + w2*u2.x + w3*u3.x;
        acc.y += w0*u0.y + w1*u1.y + w2*u2.y + w3*u3.y;
    }
    for (; e < dg; ++e){
        int   c = __shfl(c_l, e, 64);
        float w = __shfl(w_l, e, 64);
        float2 u = *(const float2*)(t + (size_t)c*FD + lane*2);
        acc.x += w*u.x; acc.y += w*u.y;
    }

    if (relu){ acc.x = fmaxf(acc.x, 0.f); acc.y = fmaxf(acc.y, 0.f); }
    *(float2*)(out + (size_t)node*FD + lane*2) = acc;
}

// ---------------- final linear [N,128]@[128,40] + log_softmax ----------------
// GEMM-style: 64-row block, 320 threads (8 row-subtiles x 40 cols), Wl^T
// staged once per block (stride-41 pad -> conflict-free), then per-thread
// log-softmax over the 40 logits of one row. LDS = 62.8 KB.

__global__ __launch_bounds__(320) void k_final(const float* __restrict__ h, const float* __restrict__ Wl,
    const float* __restrict__ bl, float* __restrict__ out, int n)
{
    __shared__ float Wt[128*41];   // Wt[k*41+j] = Wl[j*128+k]
    __shared__ float xs[64*128];
    __shared__ float lg[64*41];
    const int tid  = threadIdx.x;
    const int row0 = blockIdx.x * 64;

    for (int idx4 = tid; idx4 < 1280; idx4 += 320){
        int j  = idx4 >> 5;                 // 0..39
        int k0 = (idx4 & 31) << 2;
        float4 w = ld4(Wl + j*FD + k0);
        Wt[(k0+0)*41 + j] = w.x;
        Wt[(k0+1)*41 + j] = w.y;
        Wt[(k0+2)*41 + j] = w.z;
        Wt[(k0+3)*41 + j] = w.w;
    }
    for (int idx4 = tid; idx4 < 2048; idx4 += 320){
        int r = idx4 >> 5, kq = idx4 & 31;
        int row = row0 + r;
        float4 v = make_float4(0.f,0.f,0.f,0.f);
        if (row < n) v = ld4(h + (size_t)row*FD + kq*4);
        *(float4*)&xs[r*128 + kq*4] = v;
    }
    __syncthreads();

    const int c  = tid % 40;
    const int rb = tid / 40;      // 0..7
    float acc[8];
    #pragma unroll
    for (int i = 0; i < 8; ++i) acc[i] = 0.f;
    #pragma unroll 4
    for (int k = 0; k < 128; ++k){
        float w = Wt[k*41 + c];
        #pragma unroll
        for (int i = 0; i < 8; ++i) acc[i] += xs[(rb*8+i)*128 + k] * w;
    }
    float bv = bl[c];
    #pragma unroll
    for (int i = 0; i < 8; ++i) lg[(rb*8+i)*41 + c] = acc[i] + bv;
    __syncthreads();

    if (tid < 64){
        int row = row0 + tid;
        if (row < n){
            float v[40];
            #pragma unroll
            for (int j = 0; j < 40; ++j) v[j] = lg[tid*41 + j];
            float m = v[0];
            #pragma unroll
            for (int j = 1; j < 40; ++j) m = fmaxf(m, v[j]);
            float s = 0.f;
            #pragma unroll
            for (int j = 0; j < 40; ++j) s += expf(v[j] - m);
            float lse = m + logf(s);
            float* o = out + (size_t)row*40;
            #pragma unroll
            for (int j4 = 0; j4 < 10; ++j4){
                *(float4*)(o + 4*j4) = make_float4(v[4*j4+0]-lse, v[4*j4+1]-lse,
                                                   v[4*j4+2]-lse, v[4*j4+3]-lse);
            }
        }
    }
}

// ---------------- launch ----------------

extern "C" void kernel_launch(void* const* d_in, const int* in_sizes, int n_in,
                              void* d_out, int out_size, void* d_ws, size_t ws_size,
                              hipStream_t stream)
{
    const float* x   = (const float*)d_in[0];
    const int*   ei  = (const int*)d_in[1];     // harness ABI: integer -> int32
    const float* W1  = (const float*)d_in[2];
    const float* b1  = (const float*)d_in[3];
    const float* W2  = (const float*)d_in[4];
    const float* b2  = (const float*)d_in[5];
    const float* Wl  = (const float*)d_in[6];
    const float* bl  = (const float*)d_in[7];
    float*       out = (float*)d_out;

    const int n = in_sizes[0] / FD;
    const int e = in_sizes[1] / 2;
    const int* src = ei;
    const int* dst = ei + e;

    // workspace carve-out (256B aligned); REQUIRES ~64.2 MB:
    //   cnt 0.2MB + bcol 12.8MB + t 25.6MB + h 25.6MB
    char* p = (char*)d_ws;
    auto alloc = [&](size_t bytes)->char* {
        char* q = p; p += (bytes + 255) & ~(size_t)255; return q;
    };
    int*   cnt  = (int*)  alloc((size_t)n*4);
    int*   bcol = (int*)  alloc((size_t)n*CAP*4);
    float* t    = (float*)alloc((size_t)n*FD*4);
    float* h    = (float*)alloc((size_t)n*FD*4);

    const int gemm_grid  = (n + 31)/32;
    const int agg_grid   = (n + 3)/4;
    const int fill_grid  = (e + 255)/256;
    const int final_grid = (n + 63)/64;

    // 1. t = x @ W1^T   (also zeroes cnt for k_fill)
    hipLaunchKernelGGL(k_gemm, dim3(gemm_grid), dim3(256), 0, stream, x, W1, t, n, cnt, n);
    // 2. bucket edges by dst
    hipLaunchKernelGGL(k_fill, dim3(fill_grid), dim3(256), 0, stream, src, dst, cnt, bcol, e);
    // 3. h = relu(agg(t) + b1)
    hipLaunchKernelGGL(k_agg,  dim3(agg_grid),  dim3(256), 0, stream, t, b1, cnt, bcol, h, n, 1);
    // 4. t = h @ W2^T
    hipLaunchKernelGGL(k_gemm, dim3(gemm_grid), dim3(256), 0, stream, h, W2, t, n, (int*)nullptr, 0);
    // 5. h = relu(agg(t) + b2)
    hipLaunchKernelGGL(k_agg,  dim3(agg_grid),  dim3(256), 0, stream, t, b2, cnt, bcol, h, n, 1);
    // 6. out = log_softmax(h @ Wl^T + bl)
    hipLaunchKernelGGL(k_final, dim3(final_grid), dim3(320), 0, stream, h, Wl, bl, out, n);
}

// Round 13
// 316.776 us; speedup vs baseline: 1.0409x; 1.0409x over previous
//
#include <hip/hip_runtime.h>
#include <math.h>

#define FD  128   // feature dim
#define CAP 64    // adjacency bucket capacity; deg~Poisson(12): P(deg>64)*N ~ 1e-16 -> no drops

// R12 post-mortem: fp32 LDS-tiled GEMM measured 51-56us, VALUBusy 37%,
// occupancy 16%, bank-conflicts 0, HBM 9.5% -> latency/issue-bound at 2
// waves/SIMD. Replaced with LDS-free MFMA bf16 hi/lo-split GEMM
// (out = Ah*Wh + Ah*Wl + Al*Wh, ~2^-16 rel precision, memory-bound ~8us floor).

static __device__ __forceinline__ float4 ld4(const float* p){ return *(const float4*)p; }

typedef __attribute__((ext_vector_type(8))) short bf16x8;
typedef __attribute__((ext_vector_type(4))) float f32x4;

// round-to-nearest-even fp32 -> bf16 (no NaN handling needed for this data)
static __device__ __forceinline__ unsigned short f2bf(float f){
    union { float f; unsigned u; } c; c.f = f;
    unsigned u = c.u + 0x7fffu + ((c.u >> 16) & 1u);
    return (unsigned short)(u >> 16);
}
static __device__ __forceinline__ float bf2f(unsigned short b){
    union { float f; unsigned u; } c; c.u = ((unsigned)b) << 16;
    return c.f;
}

// ---------------- W conversion + cnt zero (runs first every call) ----------------
// Converts W1,W2 fp32[128x128] -> bf16 hi/lo planes (row-major, L2-resident),
// and zeroes cnt[0..n) for k_fill. Grid covers max(n, FD*FD) threads.

__global__ __launch_bounds__(256) void k_wconv(const float* __restrict__ W1, const float* __restrict__ W2,
                                               unsigned short* __restrict__ w1h, unsigned short* __restrict__ w1l,
                                               unsigned short* __restrict__ w2h, unsigned short* __restrict__ w2l,
                                               int* __restrict__ cnt, int n)
{
    int i = blockIdx.x*256 + threadIdx.x;
    if (i < n) cnt[i] = 0;
    if (i < FD*FD){
        float a = W1[i];
        unsigned short ah = f2bf(a);
        w1h[i] = ah; w1l[i] = f2bf(a - bf2f(ah));
        float b = W2[i];
        unsigned short bh = f2bf(b);
        w2h[i] = bh; w2l[i] = f2bf(b - bf2f(bh));
    }
}

// ---------------- edge bucketing ----------------
// cnt[d] ends as true in-degree (excl self-loop); bcol[d*CAP + 0..deg) = sources.

__global__ __launch_bounds__(256) void k_fill(const int* __restrict__ src, const int* __restrict__ dst,
                                              int* __restrict__ cnt, int* __restrict__ bcol, int e){
    int i = blockIdx.x*blockDim.x + threadIdx.x;
    if (i < e){
        int s = src[i], d = dst[i];
        int pos = atomicAdd(&cnt[d], 1);
        if (pos < CAP) bcol[d*CAP + pos] = s;
    }
}

// ---------------- MFMA GEMM: out[i][j] = sum_k A[i][k]*W[j][k] ----------------
// bf16 hi/lo split: out = Ah*Wh + Ah*Wl + Al*Wh (3 MFMAs per 16x16x32 step).
// One wave per 16-row strip; NO LDS, no barriers. A loaded fp32 from HBM and
// split in-register; W frags read from the L2-resident bf16 planes.
// Fragment maps (m89-verified family): A[l&15][8*(l>>4)+e], B[8*(l>>4)+e][l&15]
// with B = W^T  => lane reads 16 contiguous bytes of row-major W at row
// (16*jt + (l&15)), ushort offset 32*kt + 8*(l>>4).  D: col=l&15, row=(l>>4)*4+r.

__global__ __launch_bounds__(256) void k_gemm_mfma(const float* __restrict__ A,
                                                   const unsigned short* __restrict__ Wh,
                                                   const unsigned short* __restrict__ Wl,
                                                   float* __restrict__ out, int nrows)
{
    const int lane = threadIdx.x & 63;
    const int wid  = (blockIdx.x*blockDim.x + threadIdx.x) >> 6;   // global wave id
    const int i0   = wid * 16;
    if (i0 >= nrows) return;

    const int mr = lane & 15;      // frag row within strip / D col
    const int kg = lane >> 4;      // k-group 0..3

    int arow = i0 + mr;
    if (arow >= nrows) arow = nrows - 1;          // tail clamp (stores guarded)
    const float* ap = A + (size_t)arow*FD + kg*8;

    // ---- load A strip (4 k-tiles x 8 fp32 per lane), split to bf16 hi/lo ----
    bf16x8 ahf[4], alf[4];
    #pragma unroll
    for (int kt = 0; kt < 4; ++kt){
        float4 a0 = ld4(ap + 32*kt);
        float4 a1 = ld4(ap + 32*kt + 4);
        float v0 = a0.x, v1 = a0.y, v2 = a0.z, v3 = a0.w;
        float v4 = a1.x, v5 = a1.y, v6 = a1.z, v7 = a1.w;
        unsigned short h0=f2bf(v0),h1=f2bf(v1),h2=f2bf(v2),h3=f2bf(v3);
        unsigned short h4=f2bf(v4),h5=f2bf(v5),h6=f2bf(v6),h7=f2bf(v7);
        ahf[kt][0]=(short)h0; ahf[kt][1]=(short)h1; ahf[kt][2]=(short)h2; ahf[kt][3]=(short)h3;
        ahf[kt][4]=(short)h4; ahf[kt][5]=(short)h5; ahf[kt][6]=(short)h6; ahf[kt][7]=(short)h7;
        alf[kt][0]=(short)f2bf(v0-bf2f(h0)); alf[kt][1]=(short)f2bf(v1-bf2f(h1));
        alf[kt][2]=(short)f2bf(v2-bf2f(h2)); alf[kt][3]=(short)f2bf(v3-bf2f(h3));
        alf[kt][4]=(short)f2bf(v4-bf2f(h4)); alf[kt][5]=(short)f2bf(v5-bf2f(h5));
        alf[kt][6]=(short)f2bf(v6-bf2f(h6)); alf[kt][7]=(short)f2bf(v7-bf2f(h7));
    }

    f32x4 acc[8];
    #pragma unroll
    for (int jt = 0; jt < 8; ++jt){ acc[jt][0]=0.f; acc[jt][1]=0.f; acc[jt][2]=0.f; acc[jt][3]=0.f; }

    // ---- K loop: 4 k-tiles x 8 j-tiles x 3 split-MFMAs ----
    #pragma unroll
    for (int kt = 0; kt < 4; ++kt){
        #pragma unroll
        for (int jt = 0; jt < 8; ++jt){
            size_t off = (size_t)(16*jt + mr)*FD + 32*kt + 8*kg;   // ushort index, 16B aligned
            bf16x8 wh = *(const bf16x8*)(Wh + off);
            bf16x8 wl = *(const bf16x8*)(Wl + off);
            acc[jt] = __builtin_amdgcn_mfma_f32_16x16x32_bf16(ahf[kt], wh, acc[jt], 0, 0, 0);
            acc[jt] = __builtin_amdgcn_mfma_f32_16x16x32_bf16(ahf[kt], wl, acc[jt], 0, 0, 0);
            acc[jt] = __builtin_amdgcn_mfma_f32_16x16x32_bf16(alf[kt], wh, acc[jt], 0, 0, 0);
        }
    }

    // ---- store: D row = i0 + kg*4 + r, col = 16*jt + mr ----
    #pragma unroll
    for (int r = 0; r < 4; ++r){
        int orow = i0 + kg*4 + r;
        if (orow < nrows){
            float* op = out + (size_t)orow*FD + mr;
            #pragma unroll
            for (int jt = 0; jt < 8; ++jt) op[16*jt] = acc[jt][r];
        }
    }
}

// ---------------- aggregation (unchanged from R12 — isolate the GEMM change) ----------------
// out[i] = relu(b + dinv_i^2 * t[i] + sum_e dinv_i*dinv_src * t[src_e])

__global__ __launch_bounds__(256) void k_agg(const float* __restrict__ t, const float* __restrict__ bias,
    const int* __restrict__ cnt, const int* __restrict__ bcol,
    float* __restrict__ out, int n, int relu)
{
    int node = (blockIdx.x*blockDim.x + threadIdx.x) >> 6;
    int lane = threadIdx.x & 63;
    if (node >= n) return;

    float2 b   = *(const float2*)(bias + lane*2);
    int deg = cnt[node];
    int dg  = min(deg, CAP);
    float dv = rsqrtf((float)(deg + 1));       // +1: self-loop appended by reference

    int   c_l = 0; float w_l = 0.f;
    if (lane < dg){
        c_l = bcol[node*CAP + lane];
        w_l = dv * rsqrtf((float)(cnt[c_l] + 1));
    }

    float2 acc = *(const float2*)(t + (size_t)node*FD + lane*2);
    float sw = dv*dv;
    acc.x = acc.x*sw + b.x;
    acc.y = acc.y*sw + b.y;

    int e = 0;
    for (; e + 4 <= dg; e += 4){
        int   c0 = __shfl(c_l, e,   64), c1 = __shfl(c_l, e+1, 64);
        int   c2 = __shfl(c_l, e+2, 64), c3 = __shfl(c_l, e+3, 64);
        float w0 = __shfl(w_l, e,   64), w1 = __shfl(w_l, e+1, 64);
        float w2 = __shfl(w_l, e+2, 64), w3 = __shfl(w_l, e+3, 64);
        float2 u0 = *(const float2*)(t + (size_t)c0*FD + lane*2);
        float2 u1 = *(const float2*)(t + (size_t)c1*FD + lane*2);
        float2 u2 = *(const float2*)(t + (size_t)c2*FD + lane*2);
        float2 u3 = *(const float2*)(t + (size_t)c3*FD + lane*2);
        acc.x += w0*u0.x + w1*u1.x + w2*u2.x + w3*u3.x;
        acc.y += w0*u0.y + w1*u1.y + w2*u2.y + w3*u3.y;
    }
    for (; e < dg; ++e){
        int   c = __shfl(c_l, e, 64);
        float w = __shfl(w_l, e, 64);
        float2 u = *(const float2*)(t + (size_t)c*FD + lane*2);
        acc.x += w*u.x; acc.y += w*u.y;
    }

    if (relu){ acc.x = fmaxf(acc.x, 0.f); acc.y = fmaxf(acc.y, 0.f); }
    *(float2*)(out + (size_t)node*FD + lane*2) = acc;
}

// ---------------- final linear [N,128]@[128,40] + log_softmax (unchanged) ----------------

__global__ __launch_bounds__(320) void k_final(const float* __restrict__ h, const float* __restrict__ Wl,
    const float* __restrict__ bl, float* __restrict__ out, int n)
{
    __shared__ float Wt[128*41];   // Wt[k*41+j] = Wl[j*128+k]
    __shared__ float xs[64*128];
    __shared__ float lg[64*41];
    const int tid  = threadIdx.x;
    const int row0 = blockIdx.x * 64;

    for (int idx4 = tid; idx4 < 1280; idx4 += 320){
        int j  = idx4 >> 5;                 // 0..39
        int k0 = (idx4 & 31) << 2;
        float4 w = ld4(Wl + j*FD + k0);
        Wt[(k0+0)*41 + j] = w.x;
        Wt[(k0+1)*41 + j] = w.y;
        Wt[(k0+2)*41 + j] = w.z;
        Wt[(k0+3)*41 + j] = w.w;
    }
    for (int idx4 = tid; idx4 < 2048; idx4 += 320){
        int r = idx4 >> 5, kq = idx4 & 31;
        int row = row0 + r;
        float4 v = make_float4(0.f,0.f,0.f,0.f);
        if (row < n) v = ld4(h + (size_t)row*FD + kq*4);
        *(float4*)&xs[r*128 + kq*4] = v;
    }
    __syncthreads();

    const int c  = tid % 40;
    const int rb = tid / 40;      // 0..7
    float acc[8];
    #pragma unroll
    for (int i = 0; i < 8; ++i) acc[i] = 0.f;
    #pragma unroll 4
    for (int k = 0; k < 128; ++k){
        float w = Wt[k*41 + c];
        #pragma unroll
        for (int i = 0; i < 8; ++i) acc[i] += xs[(rb*8+i)*128 + k] * w;
    }
    float bv = bl[c];
    #pragma unroll
    for (int i = 0; i < 8; ++i) lg[(rb*8+i)*41 + c] = acc[i] + bv;
    __syncthreads();

    if (tid < 64){
        int row = row0 + tid;
        if (row < n){
            float v[40];
            #pragma unroll
            for (int j = 0; j < 40; ++j) v[j] = lg[tid*41 + j];
            float m = v[0];
            #pragma unroll
            for (int j = 1; j < 40; ++j) m = fmaxf(m, v[j]);
            float s = 0.f;
            #pragma unroll
            for (int j = 0; j < 40; ++j) s += expf(v[j] - m);
            float lse = m + logf(s);
            float* o = out + (size_t)row*40;
            #pragma unroll
            for (int j4 = 0; j4 < 10; ++j4){
                *(float4*)(o + 4*j4) = make_float4(v[4*j4+0]-lse, v[4*j4+1]-lse,
                                                   v[4*j4+2]-lse, v[4*j4+3]-lse);
            }
        }
    }
}

// ---------------- launch ----------------

extern "C" void kernel_launch(void* const* d_in, const int* in_sizes, int n_in,
                              void* d_out, int out_size, void* d_ws, size_t ws_size,
                              hipStream_t stream)
{
    const float* x   = (const float*)d_in[0];
    const int*   ei  = (const int*)d_in[1];     // harness ABI: integer -> int32
    const float* W1  = (const float*)d_in[2];
    const float* b1  = (const float*)d_in[3];
    const float* W2  = (const float*)d_in[4];
    const float* b2  = (const float*)d_in[5];
    const float* Wl  = (const float*)d_in[6];
    const float* bl  = (const float*)d_in[7];
    float*       out = (float*)d_out;

    const int n = in_sizes[0] / FD;
    const int e = in_sizes[1] / 2;
    const int* src = ei;
    const int* dst = ei + e;

    // workspace carve-out (256B aligned); ~64.3 MB
    char* p = (char*)d_ws;
    auto alloc = [&](size_t bytes)->char* {
        char* q = p; p += (bytes + 255) & ~(size_t)255; return q;
    };
    int*            cnt  = (int*)           alloc((size_t)n*4);
    int*            bcol = (int*)           alloc((size_t)n*CAP*4);
    float*          t    = (float*)         alloc((size_t)n*FD*4);
    float*          h    = (float*)         alloc((size_t)n*FD*4);
    unsigned short* w1h  = (unsigned short*)alloc((size_t)FD*FD*2);
    unsigned short* w1l  = (unsigned short*)alloc((size_t)FD*FD*2);
    unsigned short* w2h  = (unsigned short*)alloc((size_t)FD*FD*2);
    unsigned short* w2l  = (unsigned short*)alloc((size_t)FD*FD*2);

    const int strips     = (n + 15)/16;            // 16-row wave strips
    const int gemm_grid  = (strips + 3)/4;         // 4 waves (256 thr) per block
    const int agg_grid   = (n + 3)/4;
    const int fill_grid  = (e + 255)/256;
    const int final_grid = (n + 63)/64;
    const int conv_n     = (n > FD*FD) ? n : FD*FD;
    const int conv_grid  = (conv_n + 255)/256;

    // 1. zero cnt + convert W1,W2 -> bf16 hi/lo planes
    hipLaunchKernelGGL(k_wconv, dim3(conv_grid), dim3(256), 0, stream,
                       W1, W2, w1h, w1l, w2h, w2l, cnt, n);
    // 2. bucket edges by dst
    hipLaunchKernelGGL(k_fill, dim3(fill_grid), dim3(256), 0, stream, src, dst, cnt, bcol, e);
    // 3. t = x @ W1^T   (MFMA split-bf16)
    hipLaunchKernelGGL(k_gemm_mfma, dim3(gemm_grid), dim3(256), 0, stream, x, w1h, w1l, t, n);
    // 4. h = relu(agg(t) + b1)
    hipLaunchKernelGGL(k_agg,  dim3(agg_grid),  dim3(256), 0, stream, t, b1, cnt, bcol, h, n, 1);
    // 5. t = h @ W2^T
    hipLaunchKernelGGL(k_gemm_mfma, dim3(gemm_grid), dim3(256), 0, stream, h, w2h, w2l, t, n);
    // 6. h = relu(agg(t) + b2)
    hipLaunchKernelGGL(k_agg,  dim3(agg_grid),  dim3(256), 0, stream, t, b2, cnt, bcol, h, n, 1);
    // 7. out = log_softmax(h @ Wl^T + bl)
    hipLaunchKernelGGL(k_final, dim3(final_grid), dim3(320), 0, stream, h, Wl, bl, out, n);
}

// Round 15
// 281.636 us; speedup vs baseline: 1.1708x; 1.1248x over previous
//
#include <hip/hip_runtime.h>
#include <hip/hip_fp16.h>
#include <math.h>

#define FD  128   // feature dim
#define CAP 64    // adjacency bucket capacity; deg~Poisson(12): P(deg>64)*N ~ 1e-16 -> no drops

// R13 post-mortem: k_agg 47.3us x2, FETCH 146MB (random 512B gather misses
// per-XCD L2 ~44%), BW-bound at 3.7TB/s. Fix: fp16 feature table (rel 2^-11,
// negligible vs the 2^-6 reference-side floor) -> gather rows 256B, fetch ~2x
// down. GEMM writes fp16 table directly; h stays fp32 for GEMM#2/final.
// (R14 bench timed out; resubmitted unchanged — predictions pending.)

static __device__ __forceinline__ float4 ld4(const float* p){ return *(const float4*)p; }

typedef __attribute__((ext_vector_type(8))) short bf16x8;
typedef __attribute__((ext_vector_type(4))) float f32x4;

// round-to-nearest-even fp32 -> bf16
static __device__ __forceinline__ unsigned short f2bf(float f){
    union { float f; unsigned u; } c; c.f = f;
    unsigned u = c.u + 0x7fffu + ((c.u >> 16) & 1u);
    return (unsigned short)(u >> 16);
}
static __device__ __forceinline__ float bf2f(unsigned short b){
    union { float f; unsigned u; } c; c.u = ((unsigned)b) << 16;
    return c.f;
}
// packed 2xfp16 (u32) -> float2
static __device__ __forceinline__ float2 h2f2(unsigned v){
    __half2 h = *reinterpret_cast<__half2*>(&v);
    return __half22float2(h);
}

// ---------------- W conversion + cnt zero ----------------

__global__ __launch_bounds__(256) void k_wconv(const float* __restrict__ W1, const float* __restrict__ W2,
                                               unsigned short* __restrict__ w1h, unsigned short* __restrict__ w1l,
                                               unsigned short* __restrict__ w2h, unsigned short* __restrict__ w2l,
                                               int* __restrict__ cnt, int n)
{
    int i = blockIdx.x*256 + threadIdx.x;
    if (i < n) cnt[i] = 0;
    if (i < FD*FD){
        float a = W1[i];
        unsigned short ah = f2bf(a);
        w1h[i] = ah; w1l[i] = f2bf(a - bf2f(ah));
        float b = W2[i];
        unsigned short bh = f2bf(b);
        w2h[i] = bh; w2l[i] = f2bf(b - bf2f(bh));
    }
}

// ---------------- edge bucketing ----------------

__global__ __launch_bounds__(256) void k_fill(const int* __restrict__ src, const int* __restrict__ dst,
                                              int* __restrict__ cnt, int* __restrict__ bcol, int e){
    int i = blockIdx.x*blockDim.x + threadIdx.x;
    if (i < e){
        int s = src[i], d = dst[i];
        int pos = atomicAdd(&cnt[d], 1);
        if (pos < CAP) bcol[d*CAP + pos] = s;
    }
}

// ---------------- MFMA GEMM: t16[i][j] = (fp16) sum_k A[i][k]*W[j][k] ----------------
// bf16 hi/lo split (Ah*Wh + Ah*Wl + Al*Wh), fp32 A input, fp16 table output.
// One wave per 16-row strip; no LDS, no barriers. Fragment maps verified on HW
// (R13 absmax matched fp32 pipeline): A[l&15][8*(l>>4)+e], B=W^T row-contig,
// D col=l&15, row=(l>>4)*4+r.

__global__ __launch_bounds__(256) void k_gemm_mfma(const float* __restrict__ A,
                                                   const unsigned short* __restrict__ Wh,
                                                   const unsigned short* __restrict__ Wl,
                                                   __half* __restrict__ out, int nrows)
{
    const int lane = threadIdx.x & 63;
    const int wid  = (blockIdx.x*blockDim.x + threadIdx.x) >> 6;
    const int i0   = wid * 16;
    if (i0 >= nrows) return;

    const int mr = lane & 15;
    const int kg = lane >> 4;

    int arow = i0 + mr;
    if (arow >= nrows) arow = nrows - 1;          // tail clamp (stores guarded)
    const float* ap = A + (size_t)arow*FD + kg*8;

    bf16x8 ahf[4], alf[4];
    #pragma unroll
    for (int kt = 0; kt < 4; ++kt){
        float4 a0 = ld4(ap + 32*kt);
        float4 a1 = ld4(ap + 32*kt + 4);
        float v0 = a0.x, v1 = a0.y, v2 = a0.z, v3 = a0.w;
        float v4 = a1.x, v5 = a1.y, v6 = a1.z, v7 = a1.w;
        unsigned short h0=f2bf(v0),h1=f2bf(v1),h2=f2bf(v2),h3=f2bf(v3);
        unsigned short h4=f2bf(v4),h5=f2bf(v5),h6=f2bf(v6),h7=f2bf(v7);
        ahf[kt][0]=(short)h0; ahf[kt][1]=(short)h1; ahf[kt][2]=(short)h2; ahf[kt][3]=(short)h3;
        ahf[kt][4]=(short)h4; ahf[kt][5]=(short)h5; ahf[kt][6]=(short)h6; ahf[kt][7]=(short)h7;
        alf[kt][0]=(short)f2bf(v0-bf2f(h0)); alf[kt][1]=(short)f2bf(v1-bf2f(h1));
        alf[kt][2]=(short)f2bf(v2-bf2f(h2)); alf[kt][3]=(short)f2bf(v3-bf2f(h3));
        alf[kt][4]=(short)f2bf(v4-bf2f(h4)); alf[kt][5]=(short)f2bf(v5-bf2f(h5));
        alf[kt][6]=(short)f2bf(v6-bf2f(h6)); alf[kt][7]=(short)f2bf(v7-bf2f(h7));
    }

    f32x4 acc[8];
    #pragma unroll
    for (int jt = 0; jt < 8; ++jt){ acc[jt][0]=0.f; acc[jt][1]=0.f; acc[jt][2]=0.f; acc[jt][3]=0.f; }

    #pragma unroll
    for (int kt = 0; kt < 4; ++kt){
        #pragma unroll
        for (int jt = 0; jt < 8; ++jt){
            size_t off = (size_t)(16*jt + mr)*FD + 32*kt + 8*kg;
            bf16x8 wh = *(const bf16x8*)(Wh + off);
            bf16x8 wl = *(const bf16x8*)(Wl + off);
            acc[jt] = __builtin_amdgcn_mfma_f32_16x16x32_bf16(ahf[kt], wh, acc[jt], 0, 0, 0);
            acc[jt] = __builtin_amdgcn_mfma_f32_16x16x32_bf16(ahf[kt], wl, acc[jt], 0, 0, 0);
            acc[jt] = __builtin_amdgcn_mfma_f32_16x16x32_bf16(alf[kt], wh, acc[jt], 0, 0, 0);
        }
    }

    #pragma unroll
    for (int r = 0; r < 4; ++r){
        int orow = i0 + kg*4 + r;
        if (orow < nrows){
            __half* op = out + (size_t)orow*FD + mr;
            #pragma unroll
            for (int jt = 0; jt < 8; ++jt) op[16*jt] = __float2half_rn(acc[jt][r]);
        }
    }
}

// ---------------- aggregation (fp16 gather -> fp32 accum -> fp32 h) ----------------
// out[i] = relu(b + dinv_i^2 * t[i] + sum_e dinv_i*dinv_src * t[src_e])
// One wave per dst node; row = 128 fp16 = 256B; each lane loads one packed
// u32 (feats 2l,2l+1) -> full-wave 256B coalesced.

__global__ __launch_bounds__(256) void k_agg(const __half* __restrict__ t, const float* __restrict__ bias,
    const int* __restrict__ cnt, const int* __restrict__ bcol,
    float* __restrict__ out, int n, int relu)
{
    int node = (blockIdx.x*blockDim.x + threadIdx.x) >> 6;
    int lane = threadIdx.x & 63;
    if (node >= n) return;

    float2 b   = *(const float2*)(bias + lane*2);
    int deg = cnt[node];
    int dg  = min(deg, CAP);
    float dv = rsqrtf((float)(deg + 1));       // +1: self-loop appended by reference

    int   c_l = 0; float w_l = 0.f;
    if (lane < dg){
        c_l = bcol[node*CAP + lane];
        w_l = dv * rsqrtf((float)(cnt[c_l] + 1));
    }

    unsigned sv = *((const unsigned*)(t + (size_t)node*FD) + lane);
    float2 s = h2f2(sv);
    float sw = dv*dv;
    float2 acc;
    acc.x = s.x*sw + b.x;
    acc.y = s.y*sw + b.y;

    int e = 0;
    for (; e + 4 <= dg; e += 4){
        int   c0 = __shfl(c_l, e,   64), c1 = __shfl(c_l, e+1, 64);
        int   c2 = __shfl(c_l, e+2, 64), c3 = __shfl(c_l, e+3, 64);
        float w0 = __shfl(w_l, e,   64), w1 = __shfl(w_l, e+1, 64);
        float w2 = __shfl(w_l, e+2, 64), w3 = __shfl(w_l, e+3, 64);
        unsigned v0 = *((const unsigned*)(t + (size_t)c0*FD) + lane);
        unsigned v1 = *((const unsigned*)(t + (size_t)c1*FD) + lane);
        unsigned v2 = *((const unsigned*)(t + (size_t)c2*FD) + lane);
        unsigned v3 = *((const unsigned*)(t + (size_t)c3*FD) + lane);
        float2 u0 = h2f2(v0), u1 = h2f2(v1), u2 = h2f2(v2), u3 = h2f2(v3);
        acc.x += w0*u0.x + w1*u1.x + w2*u2.x + w3*u3.x;
        acc.y += w0*u0.y + w1*u1.y + w2*u2.y + w3*u3.y;
    }
    for (; e < dg; ++e){
        int   c = __shfl(c_l, e, 64);
        float w = __shfl(w_l, e, 64);
        unsigned v = *((const unsigned*)(t + (size_t)c*FD) + lane);
        float2 u = h2f2(v);
        acc.x += w*u.x; acc.y += w*u.y;
    }

    if (relu){ acc.x = fmaxf(acc.x, 0.f); acc.y = fmaxf(acc.y, 0.f); }
    *(float2*)(out + (size_t)node*FD + lane*2) = acc;
}

// ---------------- final linear [N,128]@[128,40] + log_softmax ----------------

__global__ __launch_bounds__(320) void k_final(const float* __restrict__ h, const float* __restrict__ Wl,
    const float* __restrict__ bl, float* __restrict__ out, int n)
{
    __shared__ float Wt[128*41];   // Wt[k*41+j] = Wl[j*128+k]
    __shared__ float xs[64*128];
    __shared__ float lg[64*41];
    const int tid  = threadIdx.x;
    const int row0 = blockIdx.x * 64;

    for (int idx4 = tid; idx4 < 1280; idx4 += 320){
        int j  = idx4 >> 5;                 // 0..39
        int k0 = (idx4 & 31) << 2;
        float4 w = ld4(Wl + j*FD + k0);
        Wt[(k0+0)*41 + j] = w.x;
        Wt[(k0+1)*41 + j] = w.y;
        Wt[(k0+2)*41 + j] = w.z;
        Wt[(k0+3)*41 + j] = w.w;
    }
    for (int idx4 = tid; idx4 < 2048; idx4 += 320){
        int r = idx4 >> 5, kq = idx4 & 31;
        int row = row0 + r;
        float4 v = make_float4(0.f,0.f,0.f,0.f);
        if (row < n) v = ld4(h + (size_t)row*FD + kq*4);
        *(float4*)&xs[r*128 + kq*4] = v;
    }
    __syncthreads();

    const int c  = tid % 40;
    const int rb = tid / 40;      // 0..7
    float acc[8];
    #pragma unroll
    for (int i = 0; i < 8; ++i) acc[i] = 0.f;
    #pragma unroll 4
    for (int k = 0; k < 128; ++k){
        float w = Wt[k*41 + c];
        #pragma unroll
        for (int i = 0; i < 8; ++i) acc[i] += xs[(rb*8+i)*128 + k] * w;
    }
    float bv = bl[c];
    #pragma unroll
    for (int i = 0; i < 8; ++i) lg[(rb*8+i)*41 + c] = acc[i] + bv;
    __syncthreads();

    if (tid < 64){
        int row = row0 + tid;
        if (row < n){
            float v[40];
            #pragma unroll
            for (int j = 0; j < 40; ++j) v[j] = lg[tid*41 + j];
            float m = v[0];
            #pragma unroll
            for (int j = 1; j < 40; ++j) m = fmaxf(m, v[j]);
            float s = 0.f;
            #pragma unroll
            for (int j = 0; j < 40; ++j) s += expf(v[j] - m);
            float lse = m + logf(s);
            float* o = out + (size_t)row*40;
            #pragma unroll
            for (int j4 = 0; j4 < 10; ++j4){
                *(float4*)(o + 4*j4) = make_float4(v[4*j4+0]-lse, v[4*j4+1]-lse,
                                                   v[4*j4+2]-lse, v[4*j4+3]-lse);
            }
        }
    }
}

// ---------------- launch ----------------

extern "C" void kernel_launch(void* const* d_in, const int* in_sizes, int n_in,
                              void* d_out, int out_size, void* d_ws, size_t ws_size,
                              hipStream_t stream)
{
    const float* x   = (const float*)d_in[0];
    const int*   ei  = (const int*)d_in[1];     // harness ABI: integer -> int32
    const float* W1  = (const float*)d_in[2];
    const float* b1  = (const float*)d_in[3];
    const float* W2  = (const float*)d_in[4];
    const float* b2  = (const float*)d_in[5];
    const float* Wl  = (const float*)d_in[6];
    const float* bl  = (const float*)d_in[7];
    float*       out = (float*)d_out;

    const int n = in_sizes[0] / FD;
    const int e = in_sizes[1] / 2;
    const int* src = ei;
    const int* dst = ei + e;

    // workspace carve-out (256B aligned); ~51.6 MB
    char* p = (char*)d_ws;
    auto alloc = [&](size_t bytes)->char* {
        char* q = p; p += (bytes + 255) & ~(size_t)255; return q;
    };
    int*            cnt  = (int*)           alloc((size_t)n*4);
    int*            bcol = (int*)           alloc((size_t)n*CAP*4);
    __half*         t16  = (__half*)        alloc((size_t)n*FD*2);
    float*          h    = (float*)         alloc((size_t)n*FD*4);
    unsigned short* w1h  = (unsigned short*)alloc((size_t)FD*FD*2);
    unsigned short* w1l  = (unsigned short*)alloc((size_t)FD*FD*2);
    unsigned short* w2h  = (unsigned short*)alloc((size_t)FD*FD*2);
    unsigned short* w2l  = (unsigned short*)alloc((size_t)FD*FD*2);

    const int strips     = (n + 15)/16;
    const int gemm_grid  = (strips + 3)/4;
    const int agg_grid   = (n + 3)/4;
    const int fill_grid  = (e + 255)/256;
    const int final_grid = (n + 63)/64;
    const int conv_n     = (n > FD*FD) ? n : FD*FD;
    const int conv_grid  = (conv_n + 255)/256;

    // 1. zero cnt + convert W1,W2 -> bf16 hi/lo planes
    hipLaunchKernelGGL(k_wconv, dim3(conv_grid), dim3(256), 0, stream,
                       W1, W2, w1h, w1l, w2h, w2l, cnt, n);
    // 2. bucket edges by dst
    hipLaunchKernelGGL(k_fill, dim3(fill_grid), dim3(256), 0, stream, src, dst, cnt, bcol, e);
    // 3. t16 = fp16(x @ W1^T)
    hipLaunchKernelGGL(k_gemm_mfma, dim3(gemm_grid), dim3(256), 0, stream, x, w1h, w1l, t16, n);
    // 4. h = relu(agg(t16) + b1)   (fp32 accum/output)
    hipLaunchKernelGGL(k_agg,  dim3(agg_grid),  dim3(256), 0, stream, t16, b1, cnt, bcol, h, n, 1);
    // 5. t16 = fp16(h @ W2^T)
    hipLaunchKernelGGL(k_gemm_mfma, dim3(gemm_grid), dim3(256), 0, stream, h, w2h, w2l, t16, n);
    // 6. h = relu(agg(t16) + b2)
    hipLaunchKernelGGL(k_agg,  dim3(agg_grid),  dim3(256), 0, stream, t16, b2, cnt, bcol, h, n, 1);
    // 7. out = log_softmax(h @ Wl^T + bl)
    hipLaunchKernelGGL(k_final, dim3(final_grid), dim3(320), 0, stream, h, Wl, bl, out, n);
}